// Round 16
// baseline (285.312 us; speedup 1.0000x reference)
//
#include <hip/hip_runtime.h>
#include <hip/hip_bf16.h>

// Shapes: B=2, S=2048, D=1024, H=16, DH=64. Inputs f32, output f32, bf16 MFMA internal.
// ws layout (shorts), preferred (54 MB): Wt[3][1024][1024] | Xbf[3][4096][1024] | Qrm | Krm | VtG
// fallback (30 MB): Wt | Qrm | Krm | VtG  (A converted in-register from f32 input)

typedef __attribute__((ext_vector_type(8))) short bf16x8;
typedef __attribute__((ext_vector_type(4))) float f32x4;

#define MFMA16(a, b, c) __builtin_amdgcn_mfma_f32_16x16x32_bf16((a), (b), (c), 0, 0, 0)

#define KSCALE 0.18033688011112042f   // log2(e)/sqrt(64)

#if __has_builtin(__builtin_amdgcn_exp2f)
#define EXP2(x) __builtin_amdgcn_exp2f(x)
#else
#define EXP2(x) exp2f(x)
#endif

__device__ __forceinline__ short f2bf_fast(float f) {
    return (short)((__builtin_bit_cast(unsigned, f) + 0x8000u) >> 16);
}
// pack [lo16=bf16(a), hi16=bf16(b)] in 3 VALU ops
__device__ __forceinline__ unsigned pack2bf(float a, float b) {
    return __builtin_amdgcn_perm(__builtin_bit_cast(unsigned, b) + 0x8000u,
                                 __builtin_bit_cast(unsigned, a) + 0x8000u,
                                 0x07060302u);
}
__device__ __forceinline__ void async_lds16(short* l, const short* g) {
    __builtin_amdgcn_global_load_lds(
        (const __attribute__((address_space(1))) void*)g,
        (__attribute__((address_space(3))) void*)l, 16, 0, 0);
}

// ---------------- Kernel 1a: weight transpose+convert (Wt[n][k] = bf16(W[k][n])) ----------------
__global__ __launch_bounds__(256) void transpose_w(const float* __restrict__ wq,
                                                   const float* __restrict__ wk,
                                                   const float* __restrict__ wv,
                                                   short* __restrict__ wt_all) {
    const int z = blockIdx.z;
    const float* W = (z == 0) ? wq : (z == 1) ? wk : wv;
    short* Wt = wt_all + z * 1048576;
    const int r0 = blockIdx.y * 64, c0 = blockIdx.x * 64;
    const int tid = threadIdx.x;

    __shared__ float t[64][68];

    #pragma unroll
    for (int r = 0; r < 4; ++r) {
        int c = tid + 256 * r;
        int row = c >> 4, ck = c & 15;
        *(f32x4*)&t[row][ck * 4] = *(const f32x4*)&W[(r0 + row) * 1024 + c0 + ck * 4];
    }
    __syncthreads();
    #pragma unroll
    for (int r = 0; r < 2; ++r) {
        int c = tid + 256 * r;
        int n = c >> 3, ck = c & 7;
        bf16x8 v;
        #pragma unroll
        for (int e = 0; e < 8; ++e) v[e] = f2bf_fast(t[ck * 8 + e][n]);
        *(bf16x8*)&Wt[(c0 + n) * 1024 + r0 + ck * 8] = v;
    }
}

// ---------------- Kernel 1b: X f32 -> bf16 one-shot ----------------
__global__ __launch_bounds__(256) void convert_x(const float* __restrict__ x0,
                                                 const float* __restrict__ x1,
                                                 const float* __restrict__ x2,
                                                 short* __restrict__ xb_all) {
    const int z = blockIdx.y;
    const float* X = (z == 0) ? x0 : (z == 1) ? x1 : x2;
    short* dst = xb_all + z * 4194304;
    int idx = blockIdx.x * 256 + threadIdx.x;
    const float* src = X + idx * 8;
    f32x4 a0 = *(const f32x4*)&src[0];
    f32x4 a1 = *(const f32x4*)&src[4];
    uint4 o;
    o.x = pack2bf(a0[0], a0[1]);
    o.y = pack2bf(a0[2], a0[3]);
    o.z = pack2bf(a1[0], a1[1]);
    o.w = pack2bf(a1[2], a1[3]);
    *(uint4*)&dst[idx * 8] = o;
}

// ---------------- Kernel 2: QKV projection GEMM v2 — register-prefetch double-buffered ------
// grid (32, 8, 3): x = m-block (fastest) -> blocks sharing an X-tile sit on one XCD.
// __launch_bounds__(256, 2): allow 256 VGPR/wave so the 8x uint4 prefetch stays in registers
// (R15 lesson: default cap of 88 spilled the prefetch to scratch -> 166 MB WRITE_SIZE).
// z=0 -> Qrm (pre-scaled by KSCALE), z=1 -> Krm, z=2 -> VtG[B,H,DH,S] (b64-packed).
__global__ __launch_bounds__(256, 2) void qkv_proj(const float* __restrict__ xq,
                                                   const float* __restrict__ xk,
                                                   const float* __restrict__ xv,
                                                   const short* __restrict__ xbf_all,
                                                   const short* __restrict__ wt_all,
                                                   const float* __restrict__ bq,
                                                   const float* __restrict__ bk,
                                                   const float* __restrict__ bv,
                                                   short* __restrict__ Qrm,
                                                   short* __restrict__ Krm,
                                                   short* __restrict__ VtG,
                                                   int use_xbf) {
    const int z = blockIdx.z;
    const float* X    = (z == 0) ? xq : (z == 1) ? xk : xv;
    const short* Xb   = xbf_all + z * 4194304;
    const short* Wt   = wt_all + z * 1048576;
    const float* bias = (z == 0) ? bq : (z == 1) ? bk : bv;

    const int m0 = blockIdx.x * 128, n0 = blockIdx.y * 128;   // swizzled: m fastest
    const int tid = threadIdx.x;
    const int lane = tid & 63, w = tid >> 6;
    const int lane15 = lane & 15, quad = lane >> 4;
    const int wm = w >> 1, wn = w & 1;

    __shared__ short As[128 * 64];
    __shared__ short Bs[128 * 64];

    f32x4 acc[4][4] = {};

    if (use_xbf) {
        // per-thread staging slots: c = r*256+tid, row = c>>3, ck = (c&7)*8
        uint4 apre[4], bpre[4];
        #pragma unroll
        for (int r = 0; r < 4; ++r) {
            int c = r * 256 + tid;
            int row = c >> 3, ck = (c & 7) * 8;
            apre[r] = *(const uint4*)&Xb[(m0 + row) * 1024 + ck];
            bpre[r] = *(const uint4*)&Wt[(n0 + row) * 1024 + ck];
        }
        for (int kt = 0; kt < 16; ++kt) {
            __syncthreads();                       // waves done reading previous LDS tile
            #pragma unroll
            for (int r = 0; r < 4; ++r) {
                int c = r * 256 + tid;
                *(uint4*)&As[c * 8] = apre[r];
                *(uint4*)&Bs[c * 8] = bpre[r];
            }
            if (kt < 15) {                         // next tile's loads: in flight across barriers
                #pragma unroll
                for (int r = 0; r < 4; ++r) {
                    int c = r * 256 + tid;
                    int row = c >> 3, ck = (c & 7) * 8;
                    apre[r] = *(const uint4*)&Xb[(m0 + row) * 1024 + (kt + 1) * 64 + ck];
                    bpre[r] = *(const uint4*)&Wt[(n0 + row) * 1024 + (kt + 1) * 64 + ck];
                }
            }
            __syncthreads();                       // staged tile visible
            #pragma unroll
            for (int ks = 0; ks < 2; ++ks) {
                bf16x8 af[4], bfr[4];
                #pragma unroll
                for (int mt = 0; mt < 4; ++mt)
                    af[mt] = *(const bf16x8*)&As[(wm * 64 + mt * 16 + lane15) * 64 + ks * 32 + quad * 8];
                #pragma unroll
                for (int nt = 0; nt < 4; ++nt)
                    bfr[nt] = *(const bf16x8*)&Bs[(wn * 64 + nt * 16 + lane15) * 64 + ks * 32 + quad * 8];
                #pragma unroll
                for (int mt = 0; mt < 4; ++mt)
                    #pragma unroll
                    for (int nt = 0; nt < 4; ++nt)
                        acc[mt][nt] = MFMA16(af[mt], bfr[nt], acc[mt][nt]);
            }
        }
    } else {
        for (int kt = 0; kt < 16; ++kt) {
            __syncthreads();
            #pragma unroll
            for (int r = 0; r < 4; ++r) {
                int c = r * 256 + tid;
                int row = c >> 3, ck = c & 7;
                async_lds16(&Bs[c * 8], &Wt[(n0 + row) * 1024 + kt * 64 + ck * 8]);
                const float* srcA = &X[(m0 + row) * 1024 + kt * 64 + ck * 8];
                f32x4 a0 = *(const f32x4*)&srcA[0];
                f32x4 a1 = *(const f32x4*)&srcA[4];
                uint4 av;
                av.x = pack2bf(a0[0], a0[1]);
                av.y = pack2bf(a0[2], a0[3]);
                av.z = pack2bf(a1[0], a1[1]);
                av.w = pack2bf(a1[2], a1[3]);
                *(uint4*)&As[c * 8] = av;
            }
            __syncthreads();
            #pragma unroll
            for (int ks = 0; ks < 2; ++ks) {
                bf16x8 af[4], bfr[4];
                #pragma unroll
                for (int mt = 0; mt < 4; ++mt)
                    af[mt] = *(const bf16x8*)&As[(wm * 64 + mt * 16 + lane15) * 64 + ks * 32 + quad * 8];
                #pragma unroll
                for (int nt = 0; nt < 4; ++nt)
                    bfr[nt] = *(const bf16x8*)&Bs[(wn * 64 + nt * 16 + lane15) * 64 + ks * 32 + quad * 8];
                #pragma unroll
                for (int mt = 0; mt < 4; ++mt)
                    #pragma unroll
                    for (int nt = 0; nt < 4; ++nt)
                        acc[mt][nt] = MFMA16(af[mt], bfr[nt], acc[mt][nt]);
            }
        }
    }

    // epilogue. C/D: col = lane15 (n), row = quad*4 + rg (m)
    if (z < 2) {
        short* dst = (z == 0) ? Qrm : Krm;
        const float sc = (z == 0) ? KSCALE : 1.0f;
        #pragma unroll
        for (int nt = 0; nt < 4; ++nt) {
            int n = n0 + wn * 64 + nt * 16 + lane15;
            float bv_ = bias[n] * sc;
            #pragma unroll
            for (int mt = 0; mt < 4; ++mt)
                #pragma unroll
                for (int rg = 0; rg < 4; ++rg) {
                    int m = m0 + wm * 64 + mt * 16 + quad * 4 + rg;
                    dst[m * 1024 + n] = f2bf_fast(fmaf(acc[mt][nt][rg], sc, bv_));
                }
        }
    } else {
        #pragma unroll
        for (int nt = 0; nt < 4; ++nt) {
            int n = n0 + wn * 64 + nt * 16 + lane15;   // d index
            float bv_ = bias[n];
            int h = n >> 6, dh = n & 63;
            #pragma unroll
            for (int mt = 0; mt < 4; ++mt) {
                int m = m0 + wm * 64 + mt * 16 + quad * 4;
                int b = m >> 11, s = m & 2047;
                uint2 pv;
                pv.x = pack2bf(acc[mt][nt][0] + bv_, acc[mt][nt][1] + bv_);
                pv.y = pack2bf(acc[mt][nt][2] + bv_, acc[mt][nt][3] + bv_);
                *(uint2*)&VtG[((b * 16 + h) * 64 + dh) * 2048 + s] = pv;
            }
        }
    }
}

// ---------------- Kernel 3: flash attention v8 — register-prefetch double-buffered staging ----
// grid (32, 16): x = bh (fastest) -> one head's q-blocks pin to one XCD (K/V L2-hot).
__global__ __launch_bounds__(512) void flash_attn(const short* __restrict__ Qrm,
                                                  const short* __restrict__ Krm,
                                                  const short* __restrict__ VtG,
                                                  float* __restrict__ out) {
    const int bh = blockIdx.x, qt = blockIdx.y;
    const int b = bh >> 4, h = bh & 15;
    const int tid = threadIdx.x, lane = tid & 63, w = tid >> 6;   // w = 0..7
    const int lane15 = lane & 15, quad = lane >> 4;
    const int q0 = qt * 128;

    __shared__ short Ks[128][80];     // K[j][d]    (stride 160 B -> 2-way banks on frags)
    __shared__ short VtS[64][144];    // V^T[d][j]  (stride 288 B)
    __shared__ short Ps[128][144];    // P[i][j], wave-private rows (i = w*16 + lane15)

    // Q fragments (B operand): B[k=d][n=i]   (Q pre-scaled by log2e/sqrt(DH))
    bf16x8 qf[2];
    #pragma unroll
    for (int kb = 0; kb < 2; ++kb)
        qf[kb] = *(const bf16x8*)&Qrm[(b * 2048 + q0 + w * 16 + lane15) * 1024
                                      + h * 64 + kb * 32 + quad * 8];

    f32x4 oacc[4] = {};
    float lacc = 0.f;

    const short* Kbase = Krm + (size_t)(b * 2048) * 1024 + h * 64;
    const short* Vbase = VtG + (size_t)(bh * 64) * 2048;

    const int c0 = tid, c1 = tid + 512;
    const int kj0 = c0 >> 3, kck0 = (c0 & 7) * 8;
    const int kj1 = c1 >> 3, kck1 = (c1 & 7) * 8;
    const int vd0 = c0 >> 4, vcj0 = (c0 & 15) * 8;
    const int vd1 = c1 >> 4, vcj1 = (c1 & 15) * 8;

    // prologue: prefetch tile 0 into registers
    uint4 kpre0 = *(const uint4*)&Kbase[(size_t)kj0 * 1024 + kck0];
    uint4 kpre1 = *(const uint4*)&Kbase[(size_t)kj1 * 1024 + kck1];
    uint4 vpre0 = *(const uint4*)&Vbase[(size_t)vd0 * 2048 + vcj0];
    uint4 vpre1 = *(const uint4*)&Vbase[(size_t)vd1 * 2048 + vcj1];

    for (int ktile = 0; ktile < 16; ++ktile) {
        const int j0n = (ktile + 1) * 128;   // next tile's j base
        __syncthreads();                      // all waves done reading previous LDS tiles
        *(uint4*)&Ks[kj0][kck0] = kpre0;
        *(uint4*)&Ks[kj1][kck1] = kpre1;
        *(uint4*)&VtS[vd0][vcj0] = vpre0;
        *(uint4*)&VtS[vd1][vcj1] = vpre1;
        if (ktile < 15) {                     // issue next tile's loads; overlap with compute
            kpre0 = *(const uint4*)&Kbase[(size_t)(j0n + kj0) * 1024 + kck0];
            kpre1 = *(const uint4*)&Kbase[(size_t)(j0n + kj1) * 1024 + kck1];
            vpre0 = *(const uint4*)&Vbase[(size_t)vd0 * 2048 + j0n + vcj0];
            vpre1 = *(const uint4*)&Vbase[(size_t)vd1 * 2048 + j0n + vcj1];
        }
        __syncthreads();                      // staged tile visible

        // ScT[j][i] = K.Q'^T + softmax, one jt-tile at a time
        #pragma unroll
        for (int jt = 0; jt < 8; ++jt) {
            bf16x8 kf0 = *(const bf16x8*)&Ks[jt * 16 + lane15][quad * 8];
            bf16x8 kf1 = *(const bf16x8*)&Ks[jt * 16 + lane15][32 + quad * 8];
            f32x4 s = {};
            s = MFMA16(kf0, qf[0], s);
            s = MFMA16(kf1, qf[1], s);
            // C-layout: col(i) = lane15, row(j) = jt*16 + quad*4 + rg
            float p0 = EXP2(s[0]), p1 = EXP2(s[1]), p2 = EXP2(s[2]), p3 = EXP2(s[3]);
            lacc += (p0 + p1) + (p2 + p3);
            uint2 pv;
            pv.x = pack2bf(p0, p1);
            pv.y = pack2bf(p2, p3);
            *(uint2*)&Ps[w * 16 + lane15][jt * 16 + quad * 4] = pv;
        }

        // O += P.V  (same-wave Ps RAW: DS in-order + compiler lgkmcnt)
        #pragma unroll
        for (int ks = 0; ks < 4; ++ks) {
            bf16x8 pf = *(const bf16x8*)&Ps[w * 16 + lane15][ks * 32 + quad * 8];
            #pragma unroll
            for (int nt = 0; nt < 4; ++nt) {
                bf16x8 vf = *(const bf16x8*)&VtS[nt * 16 + lane15][ks * 32 + quad * 8];
                oacc[nt] = MFMA16(pf, vf, oacc[nt]);
            }
        }
    }

    // reduce l across quads (lanes sharing lane15 hold disjoint j-shares)
    lacc += __shfl_xor(lacc, 16);
    lacc += __shfl_xor(lacc, 32);

    // epilogue: out[B,S,D] f32; O rows = quad*4+rg; l for that row lives at lane (quad*4+rg)
    #pragma unroll
    for (int rg = 0; rg < 4; ++rg) {
        float linv = 1.0f / __shfl(lacc, quad * 4 + rg);
        int i = q0 + w * 16 + quad * 4 + rg;
        #pragma unroll
        for (int nt = 0; nt < 4; ++nt)
            out[(b * 2048 + i) * 1024 + h * 64 + nt * 16 + lane15] = oacc[nt][rg] * linv;
    }
}

// ---------------- launcher ----------------
extern "C" void kernel_launch(void* const* d_in, const int* in_sizes, int n_in,
                              void* d_out, int out_size, void* d_ws, size_t ws_size,
                              hipStream_t stream) {
    const float* vq = (const float*)d_in[0];
    const float* vk = (const float*)d_in[1];
    const float* vv = (const float*)d_in[2];
    const float* wq = (const float*)d_in[3];
    const float* bq = (const float*)d_in[4];
    const float* wk = (const float*)d_in[5];
    const float* bk = (const float*)d_in[6];
    const float* wv = (const float*)d_in[7];
    const float* bv = (const float*)d_in[8];
    float* out = (float*)d_out;

    short* ws = (short*)d_ws;
    short* wt = ws;                                     // 3 * 1048576
    const size_t need = (size_t)(3 * 1048576 + 3 * 4194304 + 3 * 4194304) * 2;  // 54 MB
    int use_xbf = (ws_size >= need) ? 1 : 0;

    short* xbf = ws + 3 * 1048576;
    short* base = use_xbf ? (xbf + 3 * 4194304) : (ws + 3 * 1048576);
    short* Qrm = base;
    short* Krm = Qrm + 4194304;
    short* VtG = Krm + 4194304;

    transpose_w<<<dim3(16, 16, 3), 256, 0, stream>>>(wq, wk, wv, wt);
    if (use_xbf)
        convert_x<<<dim3(2048, 3), 256, 0, stream>>>(vq, vk, vv, xbf);
    qkv_proj<<<dim3(32, 8, 3), 256, 0, stream>>>(vq, vk, vv, xbf, wt,
                                                 bq, bk, bv, Qrm, Krm, VtG, use_xbf);
    flash_attn<<<dim3(32, 16), 512, 0, stream>>>(Qrm, Krm, VtG, out);
}

// Round 17
// 200.681 us; speedup vs baseline: 1.4217x; 1.4217x over previous
//
#include <hip/hip_runtime.h>
#include <hip/hip_bf16.h>

// Shapes: B=2, S=2048, D=1024, H=16, DH=64. Inputs f32, output f32, bf16 MFMA internal.
// ws layout (shorts), preferred (54 MB): Wt[3][1024][1024] | Xbf[3][4096][1024] | Qrm | Krm | VtG
// fallback (30 MB): Wt | Qrm | Krm | VtG  (A converted in-register from f32 input)

typedef __attribute__((ext_vector_type(8))) short bf16x8;
typedef __attribute__((ext_vector_type(4))) float f32x4;

#define MFMA16(a, b, c) __builtin_amdgcn_mfma_f32_16x16x32_bf16((a), (b), (c), 0, 0, 0)

#define KSCALE 0.18033688011112042f   // log2(e)/sqrt(64)

#if __has_builtin(__builtin_amdgcn_exp2f)
#define EXP2(x) __builtin_amdgcn_exp2f(x)
#else
#define EXP2(x) exp2f(x)
#endif

__device__ __forceinline__ short f2bf_fast(float f) {
    return (short)((__builtin_bit_cast(unsigned, f) + 0x8000u) >> 16);
}
// pack [lo16=bf16(a), hi16=bf16(b)] in 3 VALU ops
__device__ __forceinline__ unsigned pack2bf(float a, float b) {
    return __builtin_amdgcn_perm(__builtin_bit_cast(unsigned, b) + 0x8000u,
                                 __builtin_bit_cast(unsigned, a) + 0x8000u,
                                 0x07060302u);
}
__device__ __forceinline__ void async_lds16(short* l, const short* g) {
    __builtin_amdgcn_global_load_lds(
        (const __attribute__((address_space(1))) void*)g,
        (__attribute__((address_space(3))) void*)l, 16, 0, 0);
}

// ---------------- Kernel 1: prep — fused weight transpose (768 blocks) + X convert (6144) ----
__global__ __launch_bounds__(256) void prep(const float* __restrict__ wq,
                                            const float* __restrict__ wk,
                                            const float* __restrict__ wv,
                                            const float* __restrict__ x0,
                                            const float* __restrict__ x1,
                                            const float* __restrict__ x2,
                                            short* __restrict__ wt_all,
                                            short* __restrict__ xb_all) {
    __shared__ float t[64][68];
    const int blk = blockIdx.x;
    const int tid = threadIdx.x;
    if (blk < 768) {
        // weight transpose+convert: Wt[n][k] = bf16(W[k][n])
        const int z = blk >> 8, tile = blk & 255;
        const float* W = (z == 0) ? wq : (z == 1) ? wk : wv;
        short* Wt = wt_all + z * 1048576;
        const int r0 = (tile >> 4) * 64, c0 = (tile & 15) * 64;
        #pragma unroll
        for (int r = 0; r < 4; ++r) {
            int c = tid + 256 * r;
            int row = c >> 4, ck = c & 15;
            *(f32x4*)&t[row][ck * 4] = *(const f32x4*)&W[(r0 + row) * 1024 + c0 + ck * 4];
        }
        __syncthreads();
        #pragma unroll
        for (int r = 0; r < 2; ++r) {
            int c = tid + 256 * r;
            int n = c >> 3, ck = c & 7;
            bf16x8 v;
            #pragma unroll
            for (int e = 0; e < 8; ++e) v[e] = f2bf_fast(t[ck * 8 + e][n]);
            *(bf16x8*)&Wt[(c0 + n) * 1024 + r0 + ck * 8] = v;
        }
    } else {
        // X f32 -> bf16 one-shot
        const int idx0 = blk - 768;
        const int z = idx0 >> 11, i = idx0 & 2047;
        const float* X = (z == 0) ? x0 : (z == 1) ? x1 : x2;
        short* dst = xb_all + z * 4194304;
        int idx = i * 256 + tid;
        const float* src = X + idx * 8;
        f32x4 a0 = *(const f32x4*)&src[0];
        f32x4 a1 = *(const f32x4*)&src[4];
        uint4 o;
        o.x = pack2bf(a0[0], a0[1]);
        o.y = pack2bf(a0[2], a0[3]);
        o.z = pack2bf(a1[0], a1[1]);
        o.w = pack2bf(a1[2], a1[3]);
        *(uint4*)&dst[idx * 8] = o;
    }
}

// ---------------- Kernel 2: QKV projection GEMM (R14 async_lds16 version — known good) ------
// grid (32, 8, 3): x = m-block (fastest) -> blocks sharing an X-tile sit on one XCD.
// z=0 -> Qrm (pre-scaled by KSCALE), z=1 -> Krm, z=2 -> VtG[B,H,DH,S] (b64-packed).
__global__ __launch_bounds__(256) void qkv_proj(const float* __restrict__ xq,
                                                const float* __restrict__ xk,
                                                const float* __restrict__ xv,
                                                const short* __restrict__ xbf_all,
                                                const short* __restrict__ wt_all,
                                                const float* __restrict__ bq,
                                                const float* __restrict__ bk,
                                                const float* __restrict__ bv,
                                                short* __restrict__ Qrm,
                                                short* __restrict__ Krm,
                                                short* __restrict__ VtG,
                                                int use_xbf) {
    const int z = blockIdx.z;
    const float* X    = (z == 0) ? xq : (z == 1) ? xk : xv;
    const short* Xb   = xbf_all + z * 4194304;
    const short* Wt   = wt_all + z * 1048576;
    const float* bias = (z == 0) ? bq : (z == 1) ? bk : bv;

    const int m0 = blockIdx.x * 128, n0 = blockIdx.y * 128;   // swizzled: m fastest
    const int tid = threadIdx.x;
    const int lane = tid & 63, w = tid >> 6;
    const int lane15 = lane & 15, quad = lane >> 4;
    const int wm = w >> 1, wn = w & 1;

    __shared__ short As[128 * 64];
    __shared__ short Bs[128 * 64];

    f32x4 acc[4][4] = {};

    for (int kt = 0; kt < 16; ++kt) {
        __syncthreads();
        if (use_xbf) {
            #pragma unroll
            for (int r = 0; r < 4; ++r) {
                int c = r * 256 + tid;
                int row = c >> 3, ck = c & 7;
                async_lds16(&As[c * 8], &Xb[(m0 + row) * 1024 + kt * 64 + ck * 8]);
                async_lds16(&Bs[c * 8], &Wt[(n0 + row) * 1024 + kt * 64 + ck * 8]);
            }
        } else {
            #pragma unroll
            for (int r = 0; r < 4; ++r) {
                int c = r * 256 + tid;
                int row = c >> 3, ck = c & 7;
                async_lds16(&Bs[c * 8], &Wt[(n0 + row) * 1024 + kt * 64 + ck * 8]);
                const float* srcA = &X[(m0 + row) * 1024 + kt * 64 + ck * 8];
                f32x4 a0 = *(const f32x4*)&srcA[0];
                f32x4 a1 = *(const f32x4*)&srcA[4];
                uint4 av;
                av.x = pack2bf(a0[0], a0[1]);
                av.y = pack2bf(a0[2], a0[3]);
                av.z = pack2bf(a1[0], a1[1]);
                av.w = pack2bf(a1[2], a1[3]);
                *(uint4*)&As[c * 8] = av;
            }
        }
        __syncthreads();
        #pragma unroll
        for (int ks = 0; ks < 2; ++ks) {
            bf16x8 af[4], bfr[4];
            #pragma unroll
            for (int mt = 0; mt < 4; ++mt)
                af[mt] = *(const bf16x8*)&As[(wm * 64 + mt * 16 + lane15) * 64 + ks * 32 + quad * 8];
            #pragma unroll
            for (int nt = 0; nt < 4; ++nt)
                bfr[nt] = *(const bf16x8*)&Bs[(wn * 64 + nt * 16 + lane15) * 64 + ks * 32 + quad * 8];
            #pragma unroll
            for (int mt = 0; mt < 4; ++mt)
                #pragma unroll
                for (int nt = 0; nt < 4; ++nt)
                    acc[mt][nt] = MFMA16(af[mt], bfr[nt], acc[mt][nt]);
        }
    }

    // epilogue. C/D: col = lane15 (n), row = quad*4 + rg (m)
    if (z < 2) {
        short* dst = (z == 0) ? Qrm : Krm;
        const float sc = (z == 0) ? KSCALE : 1.0f;
        #pragma unroll
        for (int nt = 0; nt < 4; ++nt) {
            int n = n0 + wn * 64 + nt * 16 + lane15;
            float bv_ = bias[n] * sc;
            #pragma unroll
            for (int mt = 0; mt < 4; ++mt)
                #pragma unroll
                for (int rg = 0; rg < 4; ++rg) {
                    int m = m0 + wm * 64 + mt * 16 + quad * 4 + rg;
                    dst[m * 1024 + n] = f2bf_fast(fmaf(acc[mt][nt][rg], sc, bv_));
                }
        }
    } else {
        #pragma unroll
        for (int nt = 0; nt < 4; ++nt) {
            int n = n0 + wn * 64 + nt * 16 + lane15;   // d index
            float bv_ = bias[n];
            int h = n >> 6, dh = n & 63;
            #pragma unroll
            for (int mt = 0; mt < 4; ++mt) {
                int m = m0 + wm * 64 + mt * 16 + quad * 4;
                int b = m >> 11, s = m & 2047;
                uint2 pv;
                pv.x = pack2bf(acc[mt][nt][0] + bv_, acc[mt][nt][1] + bv_);
                pv.y = pack2bf(acc[mt][nt][2] + bv_, acc[mt][nt][3] + bv_);
                *(uint2*)&VtG[((b * 16 + h) * 64 + dh) * 2048 + s] = pv;
            }
        }
    }
}

// ---------------- Kernel 3: flash attention v9 — Ps chunked, 48 KB LDS -> 3 blocks/CU -------
// grid (32, 16): x = bh (fastest) -> one head's q-blocks pin to one XCD (K/V L2-hot).
// Register-prefetch K/V staging (loads in flight across barriers — R14 mechanism).
// Softmax and PV interleaved per 32-j chunk: Ps shrinks 36.9 KB -> 10 KB.
__global__ __launch_bounds__(512) void flash_attn(const short* __restrict__ Qrm,
                                                  const short* __restrict__ Krm,
                                                  const short* __restrict__ VtG,
                                                  float* __restrict__ out) {
    const int bh = blockIdx.x, qt = blockIdx.y;
    const int b = bh >> 4, h = bh & 15;
    const int tid = threadIdx.x, lane = tid & 63, w = tid >> 6;   // w = 0..7
    const int lane15 = lane & 15, quad = lane >> 4;
    const int q0 = qt * 128;

    __shared__ short Ks[128][80];     // K[j][d]    20.0 KB
    __shared__ short VtS[64][144];    // V^T[d][j]  18.0 KB
    __shared__ short Ps[128][40];     // P[i][j-chunk of 32] 10.0 KB, wave-private rows

    // Q fragments (B operand): B[k=d][n=i]   (Q pre-scaled by log2e/sqrt(DH))
    bf16x8 qf[2];
    #pragma unroll
    for (int kb = 0; kb < 2; ++kb)
        qf[kb] = *(const bf16x8*)&Qrm[(b * 2048 + q0 + w * 16 + lane15) * 1024
                                      + h * 64 + kb * 32 + quad * 8];

    f32x4 oacc[4] = {};
    float lacc = 0.f;

    const short* Kbase = Krm + (size_t)(b * 2048) * 1024 + h * 64;
    const short* Vbase = VtG + (size_t)(bh * 64) * 2048;

    const int c0 = tid, c1 = tid + 512;
    const int kj0 = c0 >> 3, kck0 = (c0 & 7) * 8;
    const int kj1 = c1 >> 3, kck1 = (c1 & 7) * 8;
    const int vd0 = c0 >> 4, vcj0 = (c0 & 15) * 8;
    const int vd1 = c1 >> 4, vcj1 = (c1 & 15) * 8;

    // prologue: prefetch tile 0 into registers
    uint4 kpre0 = *(const uint4*)&Kbase[(size_t)kj0 * 1024 + kck0];
    uint4 kpre1 = *(const uint4*)&Kbase[(size_t)kj1 * 1024 + kck1];
    uint4 vpre0 = *(const uint4*)&Vbase[(size_t)vd0 * 2048 + vcj0];
    uint4 vpre1 = *(const uint4*)&Vbase[(size_t)vd1 * 2048 + vcj1];

    for (int ktile = 0; ktile < 16; ++ktile) {
        const int j0n = (ktile + 1) * 128;   // next tile's j base
        __syncthreads();                      // all waves done reading previous LDS tiles
        *(uint4*)&Ks[kj0][kck0] = kpre0;
        *(uint4*)&Ks[kj1][kck1] = kpre1;
        *(uint4*)&VtS[vd0][vcj0] = vpre0;
        *(uint4*)&VtS[vd1][vcj1] = vpre1;
        if (ktile < 15) {                     // issue next tile's loads; overlap with compute
            kpre0 = *(const uint4*)&Kbase[(size_t)(j0n + kj0) * 1024 + kck0];
            kpre1 = *(const uint4*)&Kbase[(size_t)(j0n + kj1) * 1024 + kck1];
            vpre0 = *(const uint4*)&Vbase[(size_t)vd0 * 2048 + j0n + vcj0];
            vpre1 = *(const uint4*)&Vbase[(size_t)vd1 * 2048 + j0n + vcj1];
        }
        __syncthreads();                      // staged tile visible

        // per 32-j chunk: QK -> softmax -> PV (Ps rows wave-private; DS in-order RAW)
        #pragma unroll
        for (int ks = 0; ks < 4; ++ks) {
            #pragma unroll
            for (int half = 0; half < 2; ++half) {
                int jt = ks * 2 + half;
                bf16x8 kf0 = *(const bf16x8*)&Ks[jt * 16 + lane15][quad * 8];
                bf16x8 kf1 = *(const bf16x8*)&Ks[jt * 16 + lane15][32 + quad * 8];
                f32x4 s = {};
                s = MFMA16(kf0, qf[0], s);
                s = MFMA16(kf1, qf[1], s);
                // C-layout: col(i)=lane15, row(j)=jt*16+quad*4+rg -> local col = half*16+quad*4+rg
                float p0 = EXP2(s[0]), p1 = EXP2(s[1]), p2 = EXP2(s[2]), p3 = EXP2(s[3]);
                lacc += (p0 + p1) + (p2 + p3);
                uint2 pv;
                pv.x = pack2bf(p0, p1);
                pv.y = pack2bf(p2, p3);
                *(uint2*)&Ps[w * 16 + lane15][half * 16 + quad * 4] = pv;
            }
            bf16x8 pf = *(const bf16x8*)&Ps[w * 16 + lane15][quad * 8];
            #pragma unroll
            for (int nt = 0; nt < 4; ++nt) {
                bf16x8 vf = *(const bf16x8*)&VtS[nt * 16 + lane15][ks * 32 + quad * 8];
                oacc[nt] = MFMA16(pf, vf, oacc[nt]);
            }
        }
    }

    // reduce l across quads (lanes sharing lane15 hold disjoint j-shares)
    lacc += __shfl_xor(lacc, 16);
    lacc += __shfl_xor(lacc, 32);

    // epilogue: out[B,S,D] f32; O rows = quad*4+rg; l for that row lives at lane (quad*4+rg)
    #pragma unroll
    for (int rg = 0; rg < 4; ++rg) {
        float linv = 1.0f / __shfl(lacc, quad * 4 + rg);
        int i = q0 + w * 16 + quad * 4 + rg;
        #pragma unroll
        for (int nt = 0; nt < 4; ++nt)
            out[(b * 2048 + i) * 1024 + h * 64 + nt * 16 + lane15] = oacc[nt][rg] * linv;
    }
}

// ---------------- launcher ----------------
extern "C" void kernel_launch(void* const* d_in, const int* in_sizes, int n_in,
                              void* d_out, int out_size, void* d_ws, size_t ws_size,
                              hipStream_t stream) {
    const float* vq = (const float*)d_in[0];
    const float* vk = (const float*)d_in[1];
    const float* vv = (const float*)d_in[2];
    const float* wq = (const float*)d_in[3];
    const float* bq = (const float*)d_in[4];
    const float* wk = (const float*)d_in[5];
    const float* bk = (const float*)d_in[6];
    const float* wv = (const float*)d_in[7];
    const float* bv = (const float*)d_in[8];
    float* out = (float*)d_out;

    short* ws = (short*)d_ws;
    short* wt = ws;                                     // 3 * 1048576
    const size_t need = (size_t)(3 * 1048576 + 3 * 4194304 + 3 * 4194304) * 2;  // 54 MB
    int use_xbf = (ws_size >= need) ? 1 : 0;

    short* xbf = ws + 3 * 1048576;
    short* base = use_xbf ? (xbf + 3 * 4194304) : (ws + 3 * 1048576);
    short* Qrm = base;
    short* Krm = Qrm + 4194304;
    short* VtG = Krm + 4194304;

    prep<<<use_xbf ? 6912 : 768, 256, 0, stream>>>(wq, wk, wv, vq, vk, vv, wt, xbf);
    qkv_proj<<<dim3(32, 8, 3), 256, 0, stream>>>(vq, vk, vv, xbf, wt,
                                                 bq, bk, bv, Qrm, Krm, VtG, use_xbf);
    flash_attn<<<dim3(32, 16), 512, 0, stream>>>(Qrm, Krm, VtG, out);
}